// Round 13
// baseline (218.625 us; speedup 1.0000x reference)
//
#include <hip/hip_runtime.h>
#include <hip/hip_fp16.h>

#define NNODES 50000
#define NEDGES 800000
#define HISTB 256   // extra blocks fused into gemm1 for the histogram

__device__ __forceinline__ float leaky(float x) { return x >= 0.f ? x : 0.2f * x; }

typedef _Float16 f16x8 __attribute__((ext_vector_type(8)));
typedef float f32x4 __attribute__((ext_vector_type(4)));

struct __align__(8)  half4v { __half2 h0, h1; };
struct __align__(16) half8v { __half2 h0, h1, h2, h3; };

// ---- init: zero counters + W transpose/convert (one dispatch) --------------
__global__ __launch_bounds__(256) void init_k(const float* __restrict__ W1,
                                              const float* __restrict__ W2,
                                              const float* __restrict__ W3,
                                              __half* __restrict__ Wt,
                                              int* __restrict__ cnt) {
    int i = blockIdx.x * 256 + threadIdx.x;
    if (i < NNODES) cnt[i] = 0;
    if (i < 16384) {                       // W1: [128][128]
        int k = i >> 7, c = i & 127;
        Wt[c * 128 + k] = __float2half_rn(W1[i]);
    } else if (i < 32768) {                // W2: [128][128]
        int e = i - 16384, k = e >> 7, c = e & 127;
        Wt[16384 + c * 128 + k] = __float2half_rn(W2[e]);
    } else if (i < 40960) {                // W3: [128][64]
        int e = i - 32768, k = e >> 6, c = e & 63;
        Wt[32768 + c * 128 + k] = __float2half_rn(W3[e]);
    }
}

// ---- MFMA GEMM + fused attention dots (+ optional histogram) ---------------
template<int F, int H, bool FP16IN, bool DO_HIST>
__global__ __launch_bounds__(256) void gemm_mfma_k(const void* __restrict__ Xv,
                                                   const __half* __restrict__ Wt,
                                                   const float* __restrict__ al,
                                                   const float* __restrict__ ar,
                                                   __half* __restrict__ Yh,
                                                   float* __restrict__ el,
                                                   float* __restrict__ er, int n,
                                                   int nGemm,
                                                   const int* __restrict__ dst,
                                                   int* __restrict__ cnt,
                                                   int* __restrict__ rank) {
    constexpr int K = 128;
    constexpr int NT = F / 16;
    constexpr int LDC = F + 8;

    if (DO_HIST && blockIdx.x >= nGemm) {
        int b = blockIdx.x - nGemm;
        for (int e = b * 256 + threadIdx.x; e < NEDGES; e += HISTB * 256)
            rank[e] = atomicAdd(&cnt[dst[e]], 1);
        return;
    }

    __shared__ __align__(16) __half Cs[64 * LDC];

    const int tid = threadIdx.x;
    const int wv = tid >> 6, lane = tid & 63;
    const int cl = lane & 15, kg = lane >> 4;
    const int r0 = blockIdx.x * 64;
    const int rowA = r0 + 16 * wv + cl;
    const int rA = rowA < n ? rowA : n - 1;

    f32x4 acc[NT];
    #pragma unroll
    for (int t = 0; t < NT; t++) acc[t] = (f32x4){0.f, 0.f, 0.f, 0.f};

    #pragma unroll
    for (int ks = 0; ks < K / 32; ks++) {
        f16x8 a;
        if constexpr (FP16IN) {
            a = *(const f16x8*)((const __half*)Xv + (size_t)rA * K + ks * 32 + kg * 8);
        } else {
            const float* Xp = (const float*)Xv + (size_t)rA * K + ks * 32 + kg * 8;
            float4 x0 = *(const float4*)Xp;
            float4 x1 = *(const float4*)(Xp + 4);
            a[0] = (_Float16)x0.x; a[1] = (_Float16)x0.y;
            a[2] = (_Float16)x0.z; a[3] = (_Float16)x0.w;
            a[4] = (_Float16)x1.x; a[5] = (_Float16)x1.y;
            a[6] = (_Float16)x1.z; a[7] = (_Float16)x1.w;
        }
        #pragma unroll
        for (int t = 0; t < NT; t++) {
            f16x8 b = *(const f16x8*)(Wt + (size_t)(16 * t + cl) * K + ks * 32 + kg * 8);
            acc[t] = __builtin_amdgcn_mfma_f32_16x16x32_f16(a, b, acc[t], 0, 0, 0);
        }
    }

    // C layout col=lane&15, row=(lane>>4)*4+j [m89] -> LDS -> coalesced stores
    #pragma unroll
    for (int t = 0; t < NT; t++)
        #pragma unroll
        for (int j = 0; j < 4; j++)
            Cs[(16 * wv + 4 * kg + j) * LDC + 16 * t + cl] = __float2half_rn(acc[t][j]);
    __syncthreads();
    {
        constexpr int SEGS = F / 8;
        #pragma unroll
        for (int s = 0; s < 64 * SEGS / 256; s++) {
            int idx = s * 256 + tid;
            int row = idx / SEGS, seg = idx % SEGS;
            int grow = r0 + row;
            if (grow < n)
                *(half8v*)&Yh[(size_t)grow * F + seg * 8] =
                    *(const half8v*)&Cs[row * LDC + seg * 8];
        }
    }

    float alv[NT], arv[NT];
    #pragma unroll
    for (int t = 0; t < NT; t++) { alv[t] = al[16 * t + cl]; arv[t] = ar[16 * t + cl]; }

    if (H == 1) {
        float pl[4], pr[4];
        #pragma unroll
        for (int j = 0; j < 4; j++) {
            pl[j] = 0.f; pr[j] = 0.f;
            #pragma unroll
            for (int t = 0; t < NT; t++) { pl[j] += acc[t][j] * alv[t]; pr[j] += acc[t][j] * arv[t]; }
        }
        #pragma unroll
        for (int off = 1; off < 16; off <<= 1)
            #pragma unroll
            for (int j = 0; j < 4; j++) { pl[j] += __shfl_xor(pl[j], off); pr[j] += __shfl_xor(pr[j], off); }
        if (cl == 0)
            #pragma unroll
            for (int j = 0; j < 4; j++) {
                int row = r0 + 16 * wv + 4 * kg + j;
                if (row < n) { el[row] = pl[j]; er[row] = pr[j]; }
            }
    } else {
        float pl[4][4], pr[4][4];
        #pragma unroll
        for (int hh = 0; hh < 4; hh++)
            #pragma unroll
            for (int j = 0; j < 4; j++) {
                pl[hh][j] = acc[2 * hh][j] * alv[2 * hh] + acc[2 * hh + 1][j] * alv[2 * hh + 1];
                pr[hh][j] = acc[2 * hh][j] * arv[2 * hh] + acc[2 * hh + 1][j] * arv[2 * hh + 1];
            }
        #pragma unroll
        for (int off = 1; off < 16; off <<= 1)
            #pragma unroll
            for (int hh = 0; hh < 4; hh++)
                #pragma unroll
                for (int j = 0; j < 4; j++) {
                    pl[hh][j] += __shfl_xor(pl[hh][j], off);
                    pr[hh][j] += __shfl_xor(pr[hh][j], off);
                }
        if (cl == 0)
            #pragma unroll
            for (int j = 0; j < 4; j++) {
                int row = r0 + 16 * wv + 4 * kg + j;
                if (row < n)
                    #pragma unroll
                    for (int hh = 0; hh < 4; hh++) {
                        el[row * 4 + hh] = pl[hh][j];
                        er[row * 4 + hh] = pr[hh][j];
                    }
            }
    }
}

// ---------------- CSR scan kernels ------------------------------------------
__global__ void scan_blk_k(const int* __restrict__ cnt, int* __restrict__ offs,
                           int* __restrict__ bsum, int n) {
    __shared__ int sm[256];
    int tid = threadIdx.x;
    int i = blockIdx.x * 256 + tid;
    int v = (i < n) ? cnt[i] : 0;
    sm[tid] = v;
    __syncthreads();
    for (int off = 1; off < 256; off <<= 1) {
        int t = (tid >= off) ? sm[tid - off] : 0;
        __syncthreads();
        sm[tid] += t;
        __syncthreads();
    }
    if (i < n) offs[i] = sm[tid] - v;
    if (tid == 255) bsum[blockIdx.x] = sm[255];
}

__global__ void scan_addtop_k(int* __restrict__ offs, const int* __restrict__ bsum,
                              int n, int nb) {
    __shared__ int sm[256];
    int tid = threadIdx.x;
    int v = (tid < nb) ? bsum[tid] : 0;
    sm[tid] = v;
    __syncthreads();
    for (int off = 1; off < 256; off <<= 1) {
        int t = (tid >= off) ? sm[tid - off] : 0;
        __syncthreads();
        sm[tid] += t;
        __syncthreads();
    }
    int prefix = (blockIdx.x > 0) ? sm[blockIdx.x - 1] : 0;
    int i = blockIdx.x * 256 + tid;
    if (i < n) offs[i] += prefix;
    if (i == 0) offs[n] = NEDGES;
}

__global__ void scatter_k(const int* __restrict__ src, const int* __restrict__ dst,
                          const int* __restrict__ rank, const int* __restrict__ offs,
                          int* __restrict__ esrc) {
    int e = blockIdx.x * blockDim.x + threadIdx.x;
    if (e < NEDGES) esrc[offs[dst[e]] + rank[e]] = src[e];
}

// ---------------- agg H=4 D=32: TWO nodes per wave (one per 32-lane half) ---
// Per half: 8-edge chunks; 32 lanes compute 8x4 unnormalized p=exp(ev); inner
// loop 2 edges/iter (q=hl>>4), each lane gathering 16B. fp16 out + bias/relu.
__global__ __launch_bounds__(256) void node_agg4_k(const int* __restrict__ offs,
                                                   const int* __restrict__ esrc,
                                                   const float* __restrict__ el,
                                                   const float* __restrict__ er,
                                                   const __half* __restrict__ feat,
                                                   const float* __restrict__ bias,
                                                   __half* __restrict__ out) {
    const int lane = threadIdx.x & 63;
    const int half = lane >> 5;          // which node of the pair
    const int hl = lane & 31;
    const int hb = half * 32;            // shfl base for this half
    const int gp0 = (blockIdx.x * 256 + threadIdx.x) >> 6;   // pair index
    const int NP = (gridDim.x * 256) >> 6;

    const int h  = hl & 3;       // head for p-compute (edge slot = hl>>2, 8 slots)
    const int q  = hl >> 4;      // edge selector within 2-pack
    const int cl = hl & 15;      // col-group: cols 8cl..8cl+7
    const int hd = cl >> 2;      // head of col-group

    float4 ba = *(const float4*)&bias[8 * cl];
    float4 bb = *(const float4*)&bias[8 * cl + 4];

    for (int pair = gp0; pair * 2 < NNODES; pair += NP) {
        int wid = pair * 2 + half;
        bool valid = wid < NNODES;
        int beg = 0, end = 0;
        float erh = 0.f;
        if (valid) { beg = offs[wid]; end = offs[wid + 1]; erh = er[wid * 4 + h]; }

        float acc[8] = {0.f, 0.f, 0.f, 0.f, 0.f, 0.f, 0.f, 0.f};
        float dsum = 0.f;
        for (int base = beg; base < end; base += 8) {
            int rem = end - base;
            if (rem > 8) rem = 8;
            int sv = 0;
            if (hl < rem) sv = esrc[base + hl];
            int se = __shfl(sv, hb + (hl >> 2));
            float p = 0.f;
            if ((hl >> 2) < rem)
                p = __expf(leaky(el[se * 4 + h] + erh));
            dsum += p;
            #pragma unroll
            for (int e = 0; e < 8; e += 2) {
                if (e >= rem) break;
                int eidx = e + q;                        // <= 7 always
                int s = __shfl(sv, hb + eidx);
                float a = __shfl(p, hb + eidx * 4 + hd); // 0 for eidx >= rem
                half8v hv = *(const half8v*)&feat[(size_t)s * 128 + 8 * cl];
                float2 f0 = __half22float2(hv.h0);
                float2 f1 = __half22float2(hv.h1);
                float2 f2 = __half22float2(hv.h2);
                float2 f3 = __half22float2(hv.h3);
                acc[0] += f0.x * a; acc[1] += f0.y * a;
                acc[2] += f1.x * a; acc[3] += f1.y * a;
                acc[4] += f2.x * a; acc[5] += f2.y * a;
                acc[6] += f3.x * a; acc[7] += f3.y * a;
            }
        }
        #pragma unroll
        for (int c = 0; c < 8; c++) acc[c] += __shfl_xor(acc[c], 16);
        dsum += __shfl_xor(dsum, 4);
        dsum += __shfl_xor(dsum, 8);
        dsum += __shfl_xor(dsum, 16);
        float dh = __shfl(dsum, hb + hd);
        float inv = dh > 0.f ? 1.f / dh : 0.f;
        if (q == 0 && valid) {
            float v0 = fmaxf(acc[0] * inv + ba.x, 0.f), v1 = fmaxf(acc[1] * inv + ba.y, 0.f);
            float v2 = fmaxf(acc[2] * inv + ba.z, 0.f), v3 = fmaxf(acc[3] * inv + ba.w, 0.f);
            float v4 = fmaxf(acc[4] * inv + bb.x, 0.f), v5 = fmaxf(acc[5] * inv + bb.y, 0.f);
            float v6 = fmaxf(acc[6] * inv + bb.z, 0.f), v7 = fmaxf(acc[7] * inv + bb.w, 0.f);
            half8v hv;
            hv.h0 = __halves2half2(__float2half_rn(v0), __float2half_rn(v1));
            hv.h1 = __halves2half2(__float2half_rn(v2), __float2half_rn(v3));
            hv.h2 = __halves2half2(__float2half_rn(v4), __float2half_rn(v5));
            hv.h3 = __halves2half2(__float2half_rn(v6), __float2half_rn(v7));
            *(half8v*)&out[(size_t)wid * 128 + 8 * cl] = hv;
        }
    }
}

// ---------------- agg H=1 D=64: TWO nodes per wave ---------------------------
__global__ __launch_bounds__(256) void node_agg1_k(const int* __restrict__ offs,
                                                   const int* __restrict__ esrc,
                                                   const float* __restrict__ el,
                                                   const float* __restrict__ er,
                                                   const __half* __restrict__ feat,
                                                   const float* __restrict__ bias,
                                                   float* __restrict__ out) {
    const int lane = threadIdx.x & 63;
    const int half = lane >> 5;
    const int hl = lane & 31;
    const int hb = half * 32;
    const int gp0 = (blockIdx.x * 256 + threadIdx.x) >> 6;
    const int NP = (gridDim.x * 256) >> 6;

    const int q  = hl >> 4;      // edge selector within 2-pack
    const int cl = hl & 15;      // cols 4cl..4cl+3
    float4 b4 = *(const float4*)&bias[4 * cl];

    for (int pair = gp0; pair * 2 < NNODES; pair += NP) {
        int wid = pair * 2 + half;
        bool valid = wid < NNODES;
        int beg = 0, end = 0;
        float erd = 0.f;
        if (valid) { beg = offs[wid]; end = offs[wid + 1]; erd = er[wid]; }

        float acc[4] = {0.f, 0.f, 0.f, 0.f};
        float dsum = 0.f;
        for (int base = beg; base < end; base += 32) {
            int rem = end - base;
            if (rem > 32) rem = 32;
            int sv = 0;
            float p = 0.f;
            if (hl < rem) {
                sv = esrc[base + hl];
                p = __expf(leaky(el[sv] + erd));
            }
            dsum += p;
            #pragma unroll 4
            for (int e = 0; e < rem; e += 2) {
                int eidx = e + q;                        // <= 31 always
                int s = __shfl(sv, hb + eidx);
                float a = __shfl(p, hb + eidx);          // 0 for eidx >= rem
                half4v hv = *(const half4v*)&feat[(size_t)s * 64 + 4 * cl];
                float2 f0 = __half22float2(hv.h0);
                float2 f1 = __half22float2(hv.h1);
                acc[0] += f0.x * a; acc[1] += f0.y * a;
                acc[2] += f1.x * a; acc[3] += f1.y * a;
            }
        }
        #pragma unroll
        for (int c = 0; c < 4; c++) acc[c] += __shfl_xor(acc[c], 16);
        #pragma unroll
        for (int off = 1; off < 32; off <<= 1) dsum += __shfl_xor(dsum, off);
        float inv = dsum > 0.f ? 1.f / dsum : 0.f;
        if (q == 0 && valid) {
            *(float4*)&out[(size_t)wid * 64 + 4 * cl] =
                make_float4(acc[0] * inv + b4.x, acc[1] * inv + b4.y,
                            acc[2] * inv + b4.z, acc[3] * inv + b4.w);
        }
    }
}

extern "C" void kernel_launch(void* const* d_in, const int* in_sizes, int n_in,
                              void* d_out, int out_size, void* d_ws, size_t ws_size,
                              hipStream_t stream) {
    const float* h   = (const float*)d_in[0];
    const int*   src = (const int*)d_in[1];
    const int*   dst = (const int*)d_in[2];
    const float* W1  = (const float*)d_in[3];
    const float* al1 = (const float*)d_in[4];
    const float* ar1 = (const float*)d_in[5];
    const float* b1  = (const float*)d_in[6];
    const float* W2  = (const float*)d_in[7];
    const float* al2 = (const float*)d_in[8];
    const float* ar2 = (const float*)d_in[9];
    const float* b2  = (const float*)d_in[10];
    const float* W3  = (const float*)d_in[11];
    const float* al3 = (const float*)d_in[12];
    const float* ar3 = (const float*)d_in[13];
    const float* b3  = (const float*)d_in[14];
    float* out = (float*)d_out;

    const int n = NNODES;
    __half* feat16 = (__half*)d_ws;                         // n*128 fp16
    __half* hbuf16 = feat16 + (size_t)n * 128;              // n*128 fp16
    float*  el     = (float*)(hbuf16 + (size_t)n * 128);    // n*4
    float*  er     = el + (size_t)n * 4;                    // n*4
    int*    cnt    = (int*)(er + (size_t)n * 4);            // n
    int*    offs   = cnt + n;                               // n+1
    int*    esrc   = offs + (n + 1);                        // NEDGES
    int*    bsum   = esrc + NEDGES;                         // 256
    int*    rank   = bsum + 256;                            // NEDGES
    __half* wt     = (__half*)(rank + NEDGES);              // 40960 halfs
    __half* wt1 = wt, *wt2 = wt + 16384, *wt3 = wt + 32768;

    const int gemmBlocks = (n + 63) / 64;                   // 782
    const int nBlk = (n + 255) / 256;                       // 196
    const int eBlk = (NEDGES + 255) / 256;
    const int aggBlk = 2048;

    // ---------- init: zero counters + W transposes (one dispatch) ----------
    init_k<<<nBlk, 256, 0, stream>>>(W1, W2, W3, wt, cnt);

    // ---------- layer-1 GEMM with fused edge histogram ----------
    gemm_mfma_k<128, 4, false, true><<<gemmBlocks + HISTB, 256, 0, stream>>>(
        h, wt1, al1, ar1, feat16, el, er, n, gemmBlocks, dst, cnt, rank);

    // ---------- CSR scan + scatter ----------
    scan_blk_k<<<nBlk, 256, 0, stream>>>(cnt, offs, bsum, n);
    scan_addtop_k<<<nBlk, 256, 0, stream>>>(offs, bsum, n, nBlk);
    scatter_k<<<eBlk, 256, 0, stream>>>(src, dst, rank, offs, esrc);

    // ---------- layer 1 aggregate ----------
    node_agg4_k<<<aggBlk, 256, 0, stream>>>(offs, esrc, el, er, feat16, b1, hbuf16);

    // ---------- layer 2: 128 -> 4 heads x 32, relu ----------
    gemm_mfma_k<128, 4, true, false><<<gemmBlocks, 256, 0, stream>>>(
        hbuf16, wt2, al2, ar2, feat16, el, er, n, gemmBlocks, nullptr, nullptr, nullptr);
    node_agg4_k<<<aggBlk, 256, 0, stream>>>(offs, esrc, el, er, feat16, b2, hbuf16);

    // ---------- layer 3: 128 -> 1 head x 64, no relu ----------
    gemm_mfma_k<64, 1, true, false><<<gemmBlocks, 256, 0, stream>>>(
        hbuf16, wt3, al3, ar3, feat16, el, er, n, gemmBlocks, nullptr, nullptr, nullptr);
    node_agg1_k<<<aggBlk, 256, 0, stream>>>(offs, esrc, el, er, feat16, b3, out);
}

// Round 14
// 217.198 us; speedup vs baseline: 1.0066x; 1.0066x over previous
//
#include <hip/hip_runtime.h>
#include <hip/hip_fp16.h>

#define NNODES 50000
#define NEDGES 800000
#define HISTB 256   // extra blocks fused into gemm1 for the histogram

__device__ __forceinline__ float leaky(float x) { return x >= 0.f ? x : 0.2f * x; }

typedef _Float16 f16x8 __attribute__((ext_vector_type(8)));
typedef float f32x4 __attribute__((ext_vector_type(4)));

struct __align__(8)  half4v { __half2 h0, h1; };
struct __align__(16) half8v { __half2 h0, h1, h2, h3; };

// ---- init: zero counters + W transpose/convert (one dispatch) --------------
__global__ __launch_bounds__(256) void init_k(const float* __restrict__ W1,
                                              const float* __restrict__ W2,
                                              const float* __restrict__ W3,
                                              __half* __restrict__ Wt,
                                              int* __restrict__ cnt) {
    int i = blockIdx.x * 256 + threadIdx.x;
    if (i < NNODES) cnt[i] = 0;
    if (i < 16384) {                       // W1: [128][128]
        int k = i >> 7, c = i & 127;
        Wt[c * 128 + k] = __float2half_rn(W1[i]);
    } else if (i < 32768) {                // W2: [128][128]
        int e = i - 16384, k = e >> 7, c = e & 127;
        Wt[16384 + c * 128 + k] = __float2half_rn(W2[e]);
    } else if (i < 40960) {                // W3: [128][64]
        int e = i - 32768, k = e >> 6, c = e & 63;
        Wt[32768 + c * 128 + k] = __float2half_rn(W3[e]);
    }
}

// ---- MFMA GEMM + fused attention dots (+ optional histogram) ---------------
// CSPLIT=2: each wave does 16 rows x F/2 cols (col-half = wv&1), block=32 rows,
// 2x grid -> 2x resident waves (occupancy fix). Heads stay wave-local since
// head hh spans cols 32hh..32hh+31. CSPLIT=1: original 64-row block.
template<int F, int H, bool FP16IN, bool DO_HIST, int CSPLIT>
__global__ __launch_bounds__(256) void gemm_mfma_k(const void* __restrict__ Xv,
                                                   const __half* __restrict__ Wt,
                                                   const float* __restrict__ al,
                                                   const float* __restrict__ ar,
                                                   __half* __restrict__ Yh,
                                                   float* __restrict__ el,
                                                   float* __restrict__ er, int n,
                                                   int nGemm,
                                                   const int* __restrict__ dst,
                                                   int* __restrict__ cnt,
                                                   int* __restrict__ rank) {
    constexpr int K = 128;
    constexpr int ROWS = 64 / CSPLIT;        // rows per block
    constexpr int NTW = F / 16 / CSPLIT;     // col-tiles per wave
    constexpr int LDC = F + 8;

    if (DO_HIST && blockIdx.x >= nGemm) {
        int b = blockIdx.x - nGemm;
        for (int e = b * 256 + threadIdx.x; e < NEDGES; e += HISTB * 256)
            rank[e] = atomicAdd(&cnt[dst[e]], 1);
        return;
    }

    __shared__ __align__(16) __half Cs[ROWS * LDC];

    const int tid = threadIdx.x;
    const int wv = tid >> 6, lane = tid & 63;
    const int rs = wv / CSPLIT;              // row-strip of this wave
    const int ch = wv % CSPLIT;              // column-half of this wave
    const int cl = lane & 15, kg = lane >> 4;
    const int r0 = blockIdx.x * ROWS;
    const int rowA = r0 + 16 * rs + cl;
    const int rA = rowA < n ? rowA : n - 1;  // clamped load row (stores guarded)

    f32x4 acc[NTW];
    #pragma unroll
    for (int t = 0; t < NTW; t++) acc[t] = (f32x4){0.f, 0.f, 0.f, 0.f};

    #pragma unroll
    for (int ks = 0; ks < K / 32; ks++) {
        f16x8 a;
        if constexpr (FP16IN) {
            a = *(const f16x8*)((const __half*)Xv + (size_t)rA * K + ks * 32 + kg * 8);
        } else {
            const float* Xp = (const float*)Xv + (size_t)rA * K + ks * 32 + kg * 8;
            float4 x0 = *(const float4*)Xp;
            float4 x1 = *(const float4*)(Xp + 4);
            a[0] = (_Float16)x0.x; a[1] = (_Float16)x0.y;
            a[2] = (_Float16)x0.z; a[3] = (_Float16)x0.w;
            a[4] = (_Float16)x1.x; a[5] = (_Float16)x1.y;
            a[6] = (_Float16)x1.z; a[7] = (_Float16)x1.w;
        }
        #pragma unroll
        for (int t = 0; t < NTW; t++) {
            int tg = ch * NTW + t;
            f16x8 b = *(const f16x8*)(Wt + (size_t)(16 * tg + cl) * K + ks * 32 + kg * 8);
            acc[t] = __builtin_amdgcn_mfma_f32_16x16x32_f16(a, b, acc[t], 0, 0, 0);
        }
    }

    // C layout col=lane&15, row=(lane>>4)*4+j [m89] -> LDS -> coalesced stores
    #pragma unroll
    for (int t = 0; t < NTW; t++)
        #pragma unroll
        for (int j = 0; j < 4; j++)
            Cs[(16 * rs + 4 * kg + j) * LDC + (ch * NTW + t) * 16 + cl] =
                __float2half_rn(acc[t][j]);
    __syncthreads();
    {
        constexpr int SEGS = F / 8;
        #pragma unroll
        for (int s = 0; s < ROWS * SEGS / 256; s++) {
            int idx = s * 256 + tid;
            int row = idx / SEGS, seg = idx % SEGS;
            int grow = r0 + row;
            if (grow < n)
                *(half8v*)&Yh[(size_t)grow * F + seg * 8] =
                    *(const half8v*)&Cs[row * LDC + seg * 8];
        }
    }

    // fused attention dots (wave-local: heads align with column-halves)
    float alv[NTW], arv[NTW];
    #pragma unroll
    for (int t = 0; t < NTW; t++) {
        alv[t] = al[(ch * NTW + t) * 16 + cl];
        arv[t] = ar[(ch * NTW + t) * 16 + cl];
    }

    if (H == 1) {
        float pl[4], pr[4];
        #pragma unroll
        for (int j = 0; j < 4; j++) {
            pl[j] = 0.f; pr[j] = 0.f;
            #pragma unroll
            for (int t = 0; t < NTW; t++) { pl[j] += acc[t][j] * alv[t]; pr[j] += acc[t][j] * arv[t]; }
        }
        #pragma unroll
        for (int off = 1; off < 16; off <<= 1)
            #pragma unroll
            for (int j = 0; j < 4; j++) { pl[j] += __shfl_xor(pl[j], off); pr[j] += __shfl_xor(pr[j], off); }
        if (cl == 0)
            #pragma unroll
            for (int j = 0; j < 4; j++) {
                int row = r0 + 16 * rs + 4 * kg + j;
                if (row < n) { el[row] = pl[j]; er[row] = pr[j]; }
            }
    } else {
        constexpr int HPW = NTW / 2;           // heads per wave (2 tiles/head)
        float pl[HPW][4], pr[HPW][4];
        #pragma unroll
        for (int hh = 0; hh < HPW; hh++)
            #pragma unroll
            for (int j = 0; j < 4; j++) {
                pl[hh][j] = acc[2 * hh][j] * alv[2 * hh] + acc[2 * hh + 1][j] * alv[2 * hh + 1];
                pr[hh][j] = acc[2 * hh][j] * arv[2 * hh] + acc[2 * hh + 1][j] * arv[2 * hh + 1];
            }
        #pragma unroll
        for (int off = 1; off < 16; off <<= 1)
            #pragma unroll
            for (int hh = 0; hh < HPW; hh++)
                #pragma unroll
                for (int j = 0; j < 4; j++) {
                    pl[hh][j] += __shfl_xor(pl[hh][j], off);
                    pr[hh][j] += __shfl_xor(pr[hh][j], off);
                }
        if (cl == 0)
            #pragma unroll
            for (int j = 0; j < 4; j++) {
                int row = r0 + 16 * rs + 4 * kg + j;
                if (row < n)
                    #pragma unroll
                    for (int hh = 0; hh < HPW; hh++) {
                        el[row * H + ch * HPW + hh] = pl[hh][j];
                        er[row * H + ch * HPW + hh] = pr[hh][j];
                    }
            }
    }
}

// ---------------- CSR scan kernels ------------------------------------------
__global__ void scan_blk_k(const int* __restrict__ cnt, int* __restrict__ offs,
                           int* __restrict__ bsum, int n) {
    __shared__ int sm[256];
    int tid = threadIdx.x;
    int i = blockIdx.x * 256 + tid;
    int v = (i < n) ? cnt[i] : 0;
    sm[tid] = v;
    __syncthreads();
    for (int off = 1; off < 256; off <<= 1) {
        int t = (tid >= off) ? sm[tid - off] : 0;
        __syncthreads();
        sm[tid] += t;
        __syncthreads();
    }
    if (i < n) offs[i] = sm[tid] - v;
    if (tid == 255) bsum[blockIdx.x] = sm[255];
}

__global__ void scan_addtop_k(int* __restrict__ offs, const int* __restrict__ bsum,
                              int n, int nb) {
    __shared__ int sm[256];
    int tid = threadIdx.x;
    int v = (tid < nb) ? bsum[tid] : 0;
    sm[tid] = v;
    __syncthreads();
    for (int off = 1; off < 256; off <<= 1) {
        int t = (tid >= off) ? sm[tid - off] : 0;
        __syncthreads();
        sm[tid] += t;
        __syncthreads();
    }
    int prefix = (blockIdx.x > 0) ? sm[blockIdx.x - 1] : 0;
    int i = blockIdx.x * 256 + tid;
    if (i < n) offs[i] += prefix;
    if (i == 0) offs[n] = NEDGES;
}

__global__ void scatter_k(const int* __restrict__ src, const int* __restrict__ dst,
                          const int* __restrict__ rank, const int* __restrict__ offs,
                          int* __restrict__ esrc) {
    int e = blockIdx.x * blockDim.x + threadIdx.x;
    if (e < NEDGES) esrc[offs[dst[e]] + rank[e]] = src[e];
}

// ---------------- fused single-pass softmax+aggregate, H=4 D=32 ------------
__global__ __launch_bounds__(256) void node_agg4_k(const int* __restrict__ offs,
                                                   const int* __restrict__ esrc,
                                                   const float* __restrict__ el,
                                                   const float* __restrict__ er,
                                                   const __half* __restrict__ feat,
                                                   const float* __restrict__ bias,
                                                   __half* __restrict__ out) {
    const int lane = threadIdx.x & 63;
    const int gw0 = (blockIdx.x * 256 + threadIdx.x) >> 6;
    const int NW = (gridDim.x * 256) >> 6;

    const int h  = lane & 3;
    const int q  = lane >> 4;
    const int cl = lane & 15;
    const int hd = cl >> 2;

    float4 ba = *(const float4*)&bias[8 * cl];
    float4 bb = *(const float4*)&bias[8 * cl + 4];

    for (int wid = gw0; wid < NNODES; wid += NW) {
        int beg = offs[wid], end = offs[wid + 1];
        float erh = er[wid * 4 + h];

        float acc[8] = {0.f, 0.f, 0.f, 0.f, 0.f, 0.f, 0.f, 0.f};
        float dsum = 0.f;
        for (int base = beg; base < end; base += 16) {
            int rem = end - base;
            if (rem > 16) rem = 16;
            int sv = 0;
            if (lane < rem) sv = esrc[base + lane];
            int se = __shfl(sv, lane >> 2);
            float p = 0.f;
            if ((lane >> 2) < rem)
                p = __expf(leaky(el[se * 4 + h] + erh));
            dsum += p;
            #pragma unroll
            for (int e = 0; e < 16 && e < rem; e += 4) {
                int eidx = e + q;
                int s = __shfl(sv, eidx);
                float a = __shfl(p, eidx * 4 + hd);
                half8v hv = *(const half8v*)&feat[(size_t)s * 128 + 8 * cl];
                float2 f0 = __half22float2(hv.h0);
                float2 f1 = __half22float2(hv.h1);
                float2 f2 = __half22float2(hv.h2);
                float2 f3 = __half22float2(hv.h3);
                acc[0] += f0.x * a; acc[1] += f0.y * a;
                acc[2] += f1.x * a; acc[3] += f1.y * a;
                acc[4] += f2.x * a; acc[5] += f2.y * a;
                acc[6] += f3.x * a; acc[7] += f3.y * a;
            }
        }
        #pragma unroll
        for (int c = 0; c < 8; c++) {
            acc[c] += __shfl_xor(acc[c], 16);
            acc[c] += __shfl_xor(acc[c], 32);
        }
        #pragma unroll
        for (int off = 4; off < 64; off <<= 1) dsum += __shfl_xor(dsum, off);
        float dh = __shfl(dsum, hd);
        float inv = dh > 0.f ? 1.f / dh : 0.f;
        if (q == 0) {
            float v0 = fmaxf(acc[0] * inv + ba.x, 0.f), v1 = fmaxf(acc[1] * inv + ba.y, 0.f);
            float v2 = fmaxf(acc[2] * inv + ba.z, 0.f), v3 = fmaxf(acc[3] * inv + ba.w, 0.f);
            float v4 = fmaxf(acc[4] * inv + bb.x, 0.f), v5 = fmaxf(acc[5] * inv + bb.y, 0.f);
            float v6 = fmaxf(acc[6] * inv + bb.z, 0.f), v7 = fmaxf(acc[7] * inv + bb.w, 0.f);
            half8v hv;
            hv.h0 = __halves2half2(__float2half_rn(v0), __float2half_rn(v1));
            hv.h1 = __halves2half2(__float2half_rn(v2), __float2half_rn(v3));
            hv.h2 = __halves2half2(__float2half_rn(v4), __float2half_rn(v5));
            hv.h3 = __halves2half2(__float2half_rn(v6), __float2half_rn(v7));
            *(half8v*)&out[(size_t)wid * 128 + 8 * cl] = hv;
        }
    }
}

// ---------------- fused single-pass softmax+aggregate, H=1 D=64 ------------
__global__ __launch_bounds__(256) void node_agg1_k(const int* __restrict__ offs,
                                                   const int* __restrict__ esrc,
                                                   const float* __restrict__ el,
                                                   const float* __restrict__ er,
                                                   const __half* __restrict__ feat,
                                                   const float* __restrict__ bias,
                                                   float* __restrict__ out) {
    const int lane = threadIdx.x & 63;
    const int gw0 = (blockIdx.x * 256 + threadIdx.x) >> 6;
    const int NW = (gridDim.x * 256) >> 6;

    const int q  = lane >> 4;
    const int cl = lane & 15;
    float4 b4 = *(const float4*)&bias[4 * cl];

    for (int wid = gw0; wid < NNODES; wid += NW) {
        int beg = offs[wid], end = offs[wid + 1];
        float erd = er[wid];

        float acc[4] = {0.f, 0.f, 0.f, 0.f};
        float dsum = 0.f;
        for (int base = beg; base < end; base += 64) {
            int rem = end - base;
            if (rem > 64) rem = 64;
            int sv = 0;
            float p = 0.f;
            if (lane < rem) {
                sv = esrc[base + lane];
                p = __expf(leaky(el[sv] + erd));
            }
            dsum += p;
            #pragma unroll 4
            for (int e = 0; e < rem; e += 4) {
                int eidx = e + q;
                int s = __shfl(sv, eidx);
                float a = __shfl(p, eidx);
                half4v hv = *(const half4v*)&feat[(size_t)s * 64 + 4 * cl];
                float2 f0 = __half22float2(hv.h0);
                float2 f1 = __half22float2(hv.h1);
                acc[0] += f0.x * a; acc[1] += f0.y * a;
                acc[2] += f1.x * a; acc[3] += f1.y * a;
            }
        }
        #pragma unroll
        for (int c = 0; c < 4; c++) {
            acc[c] += __shfl_xor(acc[c], 16);
            acc[c] += __shfl_xor(acc[c], 32);
        }
        #pragma unroll
        for (int off = 1; off < 64; off <<= 1) dsum += __shfl_xor(dsum, off);
        float inv = dsum > 0.f ? 1.f / dsum : 0.f;
        if (q == 0) {
            *(float4*)&out[(size_t)wid * 64 + 4 * cl] =
                make_float4(acc[0] * inv + b4.x, acc[1] * inv + b4.y,
                            acc[2] * inv + b4.z, acc[3] * inv + b4.w);
        }
    }
}

extern "C" void kernel_launch(void* const* d_in, const int* in_sizes, int n_in,
                              void* d_out, int out_size, void* d_ws, size_t ws_size,
                              hipStream_t stream) {
    const float* h   = (const float*)d_in[0];
    const int*   src = (const int*)d_in[1];
    const int*   dst = (const int*)d_in[2];
    const float* W1  = (const float*)d_in[3];
    const float* al1 = (const float*)d_in[4];
    const float* ar1 = (const float*)d_in[5];
    const float* b1  = (const float*)d_in[6];
    const float* W2  = (const float*)d_in[7];
    const float* al2 = (const float*)d_in[8];
    const float* ar2 = (const float*)d_in[9];
    const float* b2  = (const float*)d_in[10];
    const float* W3  = (const float*)d_in[11];
    const float* al3 = (const float*)d_in[12];
    const float* ar3 = (const float*)d_in[13];
    const float* b3  = (const float*)d_in[14];
    float* out = (float*)d_out;

    const int n = NNODES;
    __half* feat16 = (__half*)d_ws;                         // n*128 fp16
    __half* hbuf16 = feat16 + (size_t)n * 128;              // n*128 fp16
    float*  el     = (float*)(hbuf16 + (size_t)n * 128);    // n*4
    float*  er     = el + (size_t)n * 4;                    // n*4
    int*    cnt    = (int*)(er + (size_t)n * 4);            // n
    int*    offs   = cnt + n;                               // n+1
    int*    esrc   = offs + (n + 1);                        // NEDGES
    int*    bsum   = esrc + NEDGES;                         // 256
    int*    rank   = bsum + 256;                            // NEDGES
    __half* wt     = (__half*)(rank + NEDGES);              // 40960 halfs
    __half* wt1 = wt, *wt2 = wt + 16384, *wt3 = wt + 32768;

    const int gemm32 = (n + 31) / 32;                       // 1563 (CSPLIT=2)
    const int gemm64 = (n + 63) / 64;                       // 782  (CSPLIT=1)
    const int nBlk = (n + 255) / 256;                       // 196
    const int eBlk = (NEDGES + 255) / 256;
    const int aggBlk = 2048;

    // ---------- init: zero counters + W transposes (one dispatch) ----------
    init_k<<<nBlk, 256, 0, stream>>>(W1, W2, W3, wt, cnt);

    // ---------- layer-1 GEMM with fused edge histogram ----------
    gemm_mfma_k<128, 4, false, true, 2><<<gemm32 + HISTB, 256, 0, stream>>>(
        h, wt1, al1, ar1, feat16, el, er, n, gemm32, dst, cnt, rank);

    // ---------- CSR scan + scatter ----------
    scan_blk_k<<<nBlk, 256, 0, stream>>>(cnt, offs, bsum, n);
    scan_addtop_k<<<nBlk, 256, 0, stream>>>(offs, bsum, n, nBlk);
    scatter_k<<<eBlk, 256, 0, stream>>>(src, dst, rank, offs, esrc);

    // ---------- layer 1 aggregate ----------
    node_agg4_k<<<aggBlk, 256, 0, stream>>>(offs, esrc, el, er, feat16, b1, hbuf16);

    // ---------- layer 2: 128 -> 4 heads x 32, relu ----------
    gemm_mfma_k<128, 4, true, false, 2><<<gemm32, 256, 0, stream>>>(
        hbuf16, wt2, al2, ar2, feat16, el, er, n, gemm32, nullptr, nullptr, nullptr);
    node_agg4_k<<<aggBlk, 256, 0, stream>>>(offs, esrc, el, er, feat16, b2, hbuf16);

    // ---------- layer 3: 128 -> 1 head x 64, no relu ----------
    gemm_mfma_k<64, 1, true, false, 1><<<gemm64, 256, 0, stream>>>(
        hbuf16, wt3, al3, ar3, feat16, el, er, n, gemm64, nullptr, nullptr, nullptr);
    node_agg1_k<<<aggBlk, 256, 0, stream>>>(offs, esrc, el, er, feat16, b3, out);
}